// Round 9
// baseline (112.254 us; speedup 1.0000x reference)
//
#include <hip/hip_runtime.h>
#include <hip/hip_bf16.h>
#include <cstdint>

#define K_DIM 768
#define M_DIM 3072
#define BS_TOTAL 16384  // B * S
#define BK 32
#define KT 24           // K_DIM / BK

typedef __attribute__((ext_vector_type(4))) float f32x4;
typedef __attribute__((ext_vector_type(8))) short bf16x8;
typedef __attribute__((ext_vector_type(4))) unsigned short u16x4;
typedef __attribute__((ext_vector_type(4))) float fv4;

typedef unsigned int u32_g __attribute__((address_space(1)));
typedef unsigned int u32_l __attribute__((address_space(3)));

static __device__ __forceinline__ void async_load16(const void* g, void* l) {
    __builtin_amdgcn_global_load_lds((const u32_g*)g, (u32_l*)l, 16, 0, 0);
}

#define BAR() __builtin_amdgcn_s_barrier()
#define SCHEDB() __builtin_amdgcn_sched_barrier(0)

static __device__ __forceinline__ unsigned short f2bf(float f) {
    unsigned u = __builtin_bit_cast(unsigned, f);
    u += 0x7fffu + ((u >> 16) & 1u);   // RNE
    return (unsigned short)(u >> 16);
}

// Merged prep: blocks [0, M_DIM) densify W rows; rest convert x to bf16.
__global__ void prep_kernel(const float* __restrict__ values,
                            const int* __restrict__ row_offsets,
                            const int* __restrict__ column_indices,
                            unsigned short* __restrict__ Wb,
                            const float* __restrict__ x,
                            unsigned short* __restrict__ xb, int n4) {
    const int b = blockIdx.x;
    const int t = threadIdx.x;
    if (b < M_DIM) {
        const int r = b;
        unsigned int* wrow32 = (unsigned int*)(Wb + (size_t)r * K_DIM);
        for (int i = t; i < K_DIM / 2; i += 256) wrow32[i] = 0u;
        __syncthreads();
        const int start = row_offsets[r], end = row_offsets[r + 1];
        unsigned short* wrow = Wb + (size_t)r * K_DIM;
        for (int i = start + t; i < end; i += 256)
            wrow[column_indices[i]] = f2bf(values[i]);
    } else {
        const int i = (b - M_DIM) * 256 + t;
        if (i < n4) {
            fv4 v = ((const fv4*)x)[i];
            u16x4 o;
            o[0] = f2bf(v[0]); o[1] = f2bf(v[1]); o[2] = f2bf(v[2]); o[3] = f2bf(v[3]);
            ((u16x4*)xb)[i] = o;
        }
    }
}

// ---- 256x256 tile, BK=32, 8 waves (2Mx4N, wave tile 128x64), dbuf LDS 64 KiB
// -> 2 blocks/CU resident (16 waves/CU: per-SIMD regs 4x~256 <= 2048, LDS
// 2x64 <= 160 KiB). One barrier + one vmcnt(0) per K-tile; the drain and each
// block's prologue/epilogue hide under the SIBLING block's MFMA (m114).
// Swizzle: 16B-block idx ^= (row>>1)&3 (measured 0 conflicts, R3/R4), applied
// on global source + ds_read addr; gload_lds dest stays linear (rule 21).

#define STAGE_A(buf, t)                                                         \
    { _Pragma("unroll") for (int c = 0; c < 2; ++c) {                           \
        const int u = c * 512 + tid;                                            \
        const int row = u >> 2;                                                 \
        const int gs = (u & 3) ^ ((row >> 1) & 3);                              \
        async_load16(X + (size_t)(row0 + row) * K_DIM + (t) * BK + gs * 8,      \
                     &sm[buf][0][(size_t)u * 8]); } }

#define STAGE_B(buf, t)                                                         \
    { _Pragma("unroll") for (int c = 0; c < 2; ++c) {                           \
        const int u = c * 512 + tid;                                            \
        const int row = u >> 2;                                                 \
        const int gs = (u & 3) ^ ((row >> 1) & 3);                              \
        async_load16(W + (size_t)(col0 + row) * K_DIM + (t) * BK + gs * 8,      \
                     &sm[buf][1][(size_t)u * 8]); } }

#define LDA(buf)                                                                \
    { _Pragma("unroll") for (int mi = 0; mi < 8; ++mi) {                        \
        const int row = wm * 128 + mi * 16 + fr;                                \
        const int blk = kq ^ ((row >> 1) & 3);                                  \
        aq[mi] = *(const bf16x8*)&sm[buf][0][row * BK + blk * 8]; } }

#define LDB(buf)                                                                \
    { _Pragma("unroll") for (int ni = 0; ni < 4; ++ni) {                        \
        const int row = wn * 64 + ni * 16 + fr;                                 \
        const int blk = kq ^ ((row >> 1) & 3);                                  \
        bq[ni] = *(const bf16x8*)&sm[buf][1][row * BK + blk * 8]; } }

#define MFMA32()                                                                \
    { __builtin_amdgcn_s_setprio(1);                                            \
      _Pragma("unroll") for (int mi = 0; mi < 8; ++mi)                          \
      _Pragma("unroll") for (int ni = 0; ni < 4; ++ni)                          \
        acc[mi][ni] = __builtin_amdgcn_mfma_f32_16x16x32_bf16(                  \
            aq[mi], bq[ni], acc[mi][ni], 0, 0, 0);                              \
      __builtin_amdgcn_s_setprio(0); }

__global__ __launch_bounds__(512, 2) void gemm_kernel(
    const unsigned short* __restrict__ X,
    const unsigned short* __restrict__ W,
    const float* __restrict__ bias,
    float* __restrict__ out) {
    __shared__ __align__(16) unsigned short sm[2][2][256 * BK];  // 64 KiB

    // R8's L2-aware mapping: per XCD 8 fixed row-panels (X slice 3 MB), bx outer.
    const int bid = blockIdx.x;           // 0..767
    const int xcd = bid & 7;
    const int j   = bid >> 3;             // 0..95
    const int by  = xcd * 8 + (j & 7);    // 0..63
    const int bx  = j >> 3;               // 0..11
    const int row0 = by * 256;
    const int col0 = bx * 256;

    const int tid  = threadIdx.x;
    const int lane = tid & 63;
    const int wave = tid >> 6;
    const int wm = wave >> 2;   // 0..1 -> A rows wm*128..+127
    const int wn = wave & 3;    // 0..3 -> B rows wn*64..+63
    const int fr = lane & 15;
    const int kq = lane >> 4;   // 0..3

    f32x4 acc[8][4] = {};
    bf16x8 aq[8], bq[4];

    // prologue: stage tile 0, load bias; single drain (prologue only)
    STAGE_A(0, 0); STAGE_B(0, 0);
    float bv[4];
#pragma unroll
    for (int ni = 0; ni < 4; ++ni) bv[ni] = bias[col0 + wn * 64 + ni * 16 + fr];
    asm volatile("s_waitcnt vmcnt(0)" ::: "memory");
    SCHEDB();
    BAR();

    for (int t = 0; t < KT; ++t) {
        const int buf = t & 1, nbuf = buf ^ 1;
        // issue next tile's staging first (long-latency), then this tile's reads
        if (t + 1 < KT) { STAGE_A(nbuf, t + 1); STAGE_B(nbuf, t + 1); }
        LDA(buf);
        LDB(buf);
        MFMA32();
        // drain own stage of nbuf; all waves' stages retired at the barrier.
        // Sibling block's MFMA covers this drain (2 blocks/CU).
        if (t + 1 < KT) {
            asm volatile("s_waitcnt vmcnt(0)" ::: "memory");
            SCHEDB();
            BAR();
        }
    }

    // epilogue: frag row = kq*4 + j, col = fr (m89-verified C/D layout)
    const int orow0 = row0 + wm * 128 + kq * 4;
#pragma unroll
    for (int mi = 0; mi < 8; ++mi)
#pragma unroll
        for (int jj = 0; jj < 4; ++jj) {
            float* op = out + (size_t)(orow0 + mi * 16 + jj) * M_DIM + col0 + wn * 64 + fr;
#pragma unroll
            for (int ni = 0; ni < 4; ++ni)
                op[ni * 16] = acc[mi][ni][jj] + bv[ni];
        }
}

extern "C" void kernel_launch(void* const* d_in, const int* in_sizes, int n_in,
                              void* d_out, int out_size, void* d_ws, size_t ws_size,
                              hipStream_t stream) {
    const float* values         = (const float*)d_in[0];
    const float* bias           = (const float*)d_in[1];
    const float* x              = (const float*)d_in[2];
    const int*   row_offsets    = (const int*)d_in[4];
    const int*   column_indices = (const int*)d_in[5];

    unsigned short* Wb = (unsigned short*)d_ws;
    unsigned short* Xb = (unsigned short*)((char*)d_ws + (size_t)M_DIM * K_DIM * 2);

    const int n4 = BS_TOTAL * K_DIM / 4;
    const int prep_blocks = M_DIM + (n4 + 255) / 256;
    prep_kernel<<<prep_blocks, 256, 0, stream>>>(values, row_offsets, column_indices,
                                                 Wb, x, Xb, n4);

    const int grid = (BS_TOTAL / 256) * (M_DIM / 256);  // 64 * 12 = 768
    gemm_kernel<<<grid, 512, 0, stream>>>(Xb, Wb, bias, (float*)d_out);
}

// Round 10
// 108.580 us; speedup vs baseline: 1.0338x; 1.0338x over previous
//
#include <hip/hip_runtime.h>
#include <hip/hip_bf16.h>
#include <cstdint>

#define K_DIM 768
#define M_DIM 3072
#define BS_TOTAL 16384  // B * S
#define KT 12           // K tiles of 64

typedef __attribute__((ext_vector_type(16))) float f32x16;
typedef __attribute__((ext_vector_type(8))) short bf16x8;
typedef __attribute__((ext_vector_type(4))) unsigned short u16x4;
typedef __attribute__((ext_vector_type(4))) float fv4;

typedef unsigned int u32_g __attribute__((address_space(1)));
typedef unsigned int u32_l __attribute__((address_space(3)));

static __device__ __forceinline__ void async_load16(const void* g, void* l) {
    __builtin_amdgcn_global_load_lds((const u32_g*)g, (u32_l*)l, 16, 0, 0);
}

#define BAR() __builtin_amdgcn_s_barrier()
#define SCHEDB() __builtin_amdgcn_sched_barrier(0)

static __device__ __forceinline__ unsigned short f2bf(float f) {
    unsigned u = __builtin_bit_cast(unsigned, f);
    u += 0x7fffu + ((u >> 16) & 1u);   // RNE
    return (unsigned short)(u >> 16);
}

// Merged prep: blocks [0, M_DIM) densify W rows; rest convert x to bf16.
__global__ void prep_kernel(const float* __restrict__ values,
                            const int* __restrict__ row_offsets,
                            const int* __restrict__ column_indices,
                            unsigned short* __restrict__ Wb,
                            const float* __restrict__ x,
                            unsigned short* __restrict__ xb, int n4) {
    const int b = blockIdx.x;
    const int t = threadIdx.x;
    if (b < M_DIM) {
        const int r = b;
        unsigned int* wrow32 = (unsigned int*)(Wb + (size_t)r * K_DIM);
        for (int i = t; i < K_DIM / 2; i += 256) wrow32[i] = 0u;
        __syncthreads();
        const int start = row_offsets[r], end = row_offsets[r + 1];
        unsigned short* wrow = Wb + (size_t)r * K_DIM;
        for (int i = start + t; i < end; i += 256)
            wrow[column_indices[i]] = f2bf(values[i]);
    } else {
        const int i = (b - M_DIM) * 256 + t;
        if (i < n4) {
            fv4 v = ((const fv4*)x)[i];
            u16x4 o;
            o[0] = f2bf(v[0]); o[1] = f2bf(v[1]); o[2] = f2bf(v[2]); o[3] = f2bf(v[3]);
            ((u16x4*)xb)[i] = o;
        }
    }
}

// ---- R8 skeleton (best measured), MFMA shape swapped to 32x32x16 ----
// 256x256 tile, BK=64, 8 waves (2Mx4N, wave tile 128x64), 8-phase, counted
// vmcnt. Per phase: 2 m-frags(32) x 1 n-frag(32) x 4 k-steps(16) = 8 MFMA.
// Pipe ceiling 4060 vs 3378 FLOP/cyc/CU; issue slots halved; ds_reads same.
// Frag addr: row holds 32 consecutive rows per lane-group -> 8 lanes per XOR'd
// 16B slot = structural optimum, 0 excess conflicts (same involution as R8).

#define STAGE_A(buf, t, half)                                                   \
    { _Pragma("unroll") for (int c = 0; c < 2; ++c) {                           \
        const int u = c * 512 + tid;                                            \
        const int row = (half) * 128 + (u >> 3);                                \
        const int gs = (u & 7) ^ (row & 7);                                     \
        async_load16(X + (size_t)(row0 + row) * K_DIM + (t) * 64 + gs * 8,      \
                     &sm[buf][0][row * 64 + (u & 7) * 8]); } }

#define STAGE_B(buf, t, half)                                                   \
    { _Pragma("unroll") for (int c = 0; c < 2; ++c) {                           \
        const int u = c * 512 + tid;                                            \
        const int row = (half) * 128 + (u >> 3);                                \
        const int gs = (u & 7) ^ (row & 7);                                     \
        async_load16(W + (size_t)(col0 + row) * K_DIM + (t) * 64 + gs * 8,      \
                     &sm[buf][1][row * 64 + (u & 7) * 8]); } }

// A frags for half mh: mi in 0..1 (32-row frags), ks in 0..3 (K=16 steps)
#define LDA(buf, mh)                                                            \
    { _Pragma("unroll") for (int mi = 0; mi < 2; ++mi)                          \
      _Pragma("unroll") for (int ks = 0; ks < 4; ++ks) {                        \
        const int row = wm * 128 + (mh) * 64 + mi * 32 + ln31;                  \
        const int g = ks * 2 + l32;                                             \
        aq[mi][ks] = *(const bf16x8*)&sm[buf][0][row * 64                       \
                                                 + ((g ^ (row & 7)) * 8)]; } }

// B frag for half nh: one 32-col frag, ks in 0..3
#define LDB(buf, nh, breg)                                                      \
    { _Pragma("unroll") for (int ks = 0; ks < 4; ++ks) {                        \
        const int row = wn * 64 + (nh) * 32 + ln31;                             \
        const int g = ks * 2 + l32;                                             \
        breg[ks] = *(const bf16x8*)&sm[buf][1][row * 64                         \
                                               + ((g ^ (row & 7)) * 8)]; } }

#define MFMA8(mh, nh, breg)                                                     \
    { __builtin_amdgcn_s_setprio(1);                                            \
      _Pragma("unroll") for (int mi = 0; mi < 2; ++mi)                          \
      _Pragma("unroll") for (int ks = 0; ks < 4; ++ks)                          \
        acc[(mh)*2+mi][nh] = __builtin_amdgcn_mfma_f32_32x32x16_bf16(           \
            aq[mi][ks], breg[ks], acc[(mh)*2+mi][nh], 0, 0, 0);                 \
      __builtin_amdgcn_s_setprio(0); }

__global__ __launch_bounds__(512, 2) void gemm_kernel(
    const unsigned short* __restrict__ X,
    const unsigned short* __restrict__ W,
    const float* __restrict__ bias,
    float* __restrict__ out) {
    __shared__ __align__(16) unsigned short sm[2][2][256 * 64];  // 128 KiB

    // R8's L2-aware mapping: per XCD 8 fixed row-panels (X slice 3 MB), bx outer.
    const int bid = blockIdx.x;           // 0..767
    const int xcd = bid & 7;
    const int j   = bid >> 3;             // 0..95
    const int by  = xcd * 8 + (j & 7);    // 0..63
    const int bx  = j >> 3;               // 0..11
    const int row0 = by * 256;
    const int col0 = bx * 256;

    const int tid  = threadIdx.x;
    const int lane = tid & 63;
    const int wave = tid >> 6;
    const int wm = wave >> 2;   // 0..1 -> A rows wm*128..+127
    const int wn = wave & 3;    // 0..3 -> B rows wn*64..+63
    const int ln31 = lane & 31;
    const int l32  = lane >> 5;

    f32x16 acc[4][2] = {};      // [m-frag 0..3][n-frag 0..1], 128 AGPR
    bf16x8 aq[2][4], b0[4], b1[4];

    // prologue: tile 0 fully + B of tile 1 (A of tile 1 staged in t=0 P0/P1)
    STAGE_A(0, 0, 0); STAGE_A(0, 0, 1);
    STAGE_B(0, 0, 0); STAGE_B(0, 0, 1);
    STAGE_B(1, 1, 0); STAGE_B(1, 1, 1);
    asm volatile("s_waitcnt vmcnt(4)" ::: "memory");  // tile 0 complete; B(1) may fly
    SCHEDB();
    BAR();

    for (int t = 0; t < KT; ++t) {
        const int buf = t & 1, nbuf = buf ^ 1;
        // ---- P0: (mh0, nh0) ----
        LDA(buf, 0);
        LDB(buf, 0, b0);
        if (t + 1 < KT) STAGE_A(nbuf, t + 1, 0);
        BAR();
        MFMA8(0, 0, b0);
        BAR();
        // ---- P1: (mh0, nh1) ----
        LDB(buf, 1, b1);
        if (t + 1 < KT) STAGE_A(nbuf, t + 1, 1);
        BAR();
        MFMA8(0, 1, b1);
        BAR();
        // ---- P2: (mh1, nh1) ----
        LDA(buf, 1);
        if (t + 2 < KT) STAGE_B(buf, t + 2, 0);
        BAR();
        MFMA8(1, 1, b1);
        BAR();
        // ---- P3: (mh1, nh0) ----
        if (t + 2 < KT) STAGE_B(buf, t + 2, 1);
        BAR();
        MFMA8(1, 0, b0);
        // counted wait, once per K-tile; never 0 in steady state
        if (t + 2 < KT)      { asm volatile("s_waitcnt vmcnt(4)" ::: "memory"); SCHEDB(); }
        else if (t + 1 < KT) { asm volatile("s_waitcnt vmcnt(0)" ::: "memory"); SCHEDB(); }
        BAR();
    }

    // epilogue: 32x32 C/D layout (m101-verified): col = lane&31,
    // row = (reg&3) + 8*(reg>>2) + 4*(lane>>5)
    float bv[2];
#pragma unroll
    for (int ni = 0; ni < 2; ++ni) bv[ni] = bias[col0 + wn * 64 + ni * 32 + ln31];

#pragma unroll
    for (int mi = 0; mi < 4; ++mi)
#pragma unroll
        for (int rq = 0; rq < 4; ++rq)      // reg>>2
#pragma unroll
            for (int rr = 0; rr < 4; ++rr) {  // reg&3
                const int m = row0 + wm * 128 + mi * 32 + rr + 8 * rq + 4 * l32;
                float* op = out + (size_t)m * M_DIM + col0 + wn * 64 + ln31;
#pragma unroll
                for (int ni = 0; ni < 2; ++ni)
                    op[ni * 32] = acc[mi][ni][rq * 4 + rr] + bv[ni];
            }
}

extern "C" void kernel_launch(void* const* d_in, const int* in_sizes, int n_in,
                              void* d_out, int out_size, void* d_ws, size_t ws_size,
                              hipStream_t stream) {
    const float* values         = (const float*)d_in[0];
    const float* bias           = (const float*)d_in[1];
    const float* x              = (const float*)d_in[2];
    const int*   row_offsets    = (const int*)d_in[4];
    const int*   column_indices = (const int*)d_in[5];

    unsigned short* Wb = (unsigned short*)d_ws;
    unsigned short* Xb = (unsigned short*)((char*)d_ws + (size_t)M_DIM * K_DIM * 2);

    const int n4 = BS_TOTAL * K_DIM / 4;
    const int prep_blocks = M_DIM + (n4 + 255) / 256;
    prep_kernel<<<prep_blocks, 256, 0, stream>>>(values, row_offsets, column_indices,
                                                 Wb, x, Xb, n4);

    const int grid = (BS_TOTAL / 256) * (M_DIM / 256);  // 64 * 12 = 768
    gemm_kernel<<<grid, 512, 0, stream>>>(Xb, Wb, bias, (float*)d_out);
}